// Round 9
// baseline (303.351 us; speedup 1.0000x reference)
//
#include <hip/hip_runtime.h>
#include <hip/hip_bf16.h>
#include <cstddef>
#include <cstdint>

// ---------------------------------------------------------------------------
// Problem constants
// ---------------------------------------------------------------------------
#define B_   128
#define N_   8
#define C_   1024
#define FS_  14
#define POS_ 196            // 14*14
#define P_   20
#define HWC_ 9              // 3*3 cells
#define CMID_ 256
#define FEATD_ 2304         // CMID*HWC
#define H1_  1024
#define O_   27
#define PROWS_ (B_*N_*HWC_) // 9216 pooled rows (bn,cell)

typedef __attribute__((ext_vector_type(8))) short bf16x8;   // 8 bf16 (4 VGPRs)
typedef __attribute__((ext_vector_type(4))) float f32x4;

// async global->LDS, 16B per lane; LDS dest = wave-uniform base + lane*16
__device__ __forceinline__ void gld16(const void* g, void* l) {
    __builtin_amdgcn_global_load_lds(
        (const __attribute__((address_space(1))) unsigned int*)g,
        (__attribute__((address_space(3))) unsigned int*)l, 16, 0, 0);
}

// ---------------------------------------------------------------------------
// Kernel 1a: split-K partials of Wc = w2 @ w1
// ---------------------------------------------------------------------------
__global__ __launch_bounds__(256) void wcombine_split_kernel(
    const float* __restrict__ w1,   // (512,1024)
    const float* __restrict__ w2,   // (256,512)
    float* __restrict__ wpart)      // (8,256,1024) fp32
{
    const int tid = threadIdx.x;
    const int tx = tid & 15, ty = tid >> 4;
    const int c0 = blockIdx.x * 64;
    const int o0 = blockIdx.y * 64;
    const int kb = blockIdx.z * 64;
    __shared__ __align__(16) float As[16][68];
    __shared__ __align__(16) float Bs[16][68];
    float acc[4][4] = {};
    for (int k0 = kb; k0 < kb + 64; k0 += 16) {
        for (int i = tid; i < 64 * 16; i += 256) {
            int k = i & 15, m = i >> 4;
            As[k][m] = w2[(size_t)(o0 + m) * 512 + k0 + k];
        }
        for (int i = tid; i < 64 * 16; i += 256) {
            int n = i & 63, k = i >> 6;
            Bs[k][n] = w1[(size_t)(k0 + k) * 1024 + c0 + n];
        }
        __syncthreads();
        #pragma unroll
        for (int k = 0; k < 16; ++k) {
            float4 a = *(const float4*)&As[k][ty * 4];
            float4 b = *(const float4*)&Bs[k][tx * 4];
            float av[4] = {a.x, a.y, a.z, a.w};
            float bv[4] = {b.x, b.y, b.z, b.w};
            #pragma unroll
            for (int i = 0; i < 4; ++i)
                #pragma unroll
                for (int j = 0; j < 4; ++j)
                    acc[i][j] += av[i] * bv[j];
        }
        __syncthreads();
    }
    float* dst = wpart + (size_t)blockIdx.z * (256 * 1024);
    for (int i = 0; i < 4; ++i) {
        float4 v = make_float4(acc[i][0], acc[i][1], acc[i][2], acc[i][3]);
        *(float4*)&dst[(size_t)(o0 + ty * 4 + i) * 1024 + c0 + tx * 4] = v;
    }
}

// ---------------------------------------------------------------------------
// Kernel 1b: Wc = bf16( sum_z wpart[z] )
// ---------------------------------------------------------------------------
__global__ __launch_bounds__(256) void wc_reduce_kernel(
    const float* __restrict__ wpart, __hip_bfloat16* __restrict__ Wc)
{
    int idx = blockIdx.x * 256 + threadIdx.x;
    float s = 0.f;
    #pragma unroll
    for (int z = 0; z < 8; ++z) s += wpart[(size_t)z * (256 * 1024) + idx];
    Wc[idx] = __float2bfloat16(s);
}

// ---------------------------------------------------------------------------
// Kernel 2: roipool via MFMA, SEPARABLE weight rows (no RMW).
//   R8 post-mortem: MFMA version stayed ~60 µs because phase 1 was a serial
//   LDS RMW chain (64 dependent ds RMWs x ~130 cy = ~4 µs/block on 72
//   threads while 184 wait). Fix: the summed 4-sample bilinear weights of a
//   cell factor EXACTLY as an outer product W_row(y,x) = ypro[y]*xpro[x]
//   (validity and the 0.25 mean are axis-separable; clamp collisions sum
//   automatically). Each row thread builds ypro[14]/xpro[14] in registers
//   with static unrolled compare-selects, then WRITES each of the 232 row
//   entries exactly once (98 bf16x2 + 18 zero-pad stores; no dependencies).
//   Phase 0b (A zeroing) deleted — every A element is written.
//   Staging, MFMA mapping, epilogue identical to R8 (which passed).
// ---------------------------------------------------------------------------
#define CCH_   64
#define SSTR_  232           // row stride in bf16 (29*8, 16B-aligned rows)
#define AROWS_ 72
#define AOFF_  (AROWS_ * SSTR_)   // Bs base offset in elems
struct bf4s { __hip_bfloat162 lo, hi; };
__global__ __launch_bounds__(256, 2) void roipool_kernel(
    const float* __restrict__ fmap,          // (128,1024,196)
    const float* __restrict__ boxes,         // (128,8,4)
    __hip_bfloat16* __restrict__ pooled)     // (9216, 1024)
{
    const int b  = blockIdx.y;
    const int c0 = blockIdx.x * CCH_;
    const int tid = threadIdx.x;
    __shared__ __align__(16) __hip_bfloat16 Ls[(AROWS_ + CCH_) * SSTR_];

    // ---- phase 0a: issue fmap chunk loads (64 rows x 49 float4) ----
    float4 vbuf[13];
    const float* src = fmap + ((size_t)b * C_ + c0) * POS_;
    #pragma unroll
    for (int it = 0; it < 13; ++it) {
        int i = tid + it * 256;
        if (i < CCH_ * 49) {
            int c = i / 49, ch = i - c * 49;
            vbuf[it] = *(const float4*)(src + (size_t)c * POS_ + ch * 4);
        }
    }

    // ---- phase 1: build A rows (separable outer product, pure writes) ----
    // Runs while the global loads are in flight (VALU hides HBM latency).
    if (tid < AROWS_) {
        const int m = tid;
        const int n = m / 9, cell = m - n * 9;
        const int chh = cell / 3, cww = cell % 3;
        float4 bx = *(const float4*)(boxes + ((size_t)b * N_ + n) * 4);
        float bw = (bx.z - bx.x) * (1.0f / 3.0f);
        float bh = (bx.w - bx.y) * (1.0f / 3.0f);
        float ypro[FS_], xpro[FS_];
        #pragma unroll
        for (int k = 0; k < FS_; ++k) { ypro[k] = 0.f; xpro[k] = 0.f; }
        #pragma unroll
        for (int s = 0; s < 2; ++s) {
            // y axis sample s
            float yy = bx.y + ((float)(2 * chh + s) + 0.5f) * 0.5f * bh;
            bool vy = (yy > -1.0f) && (yy < (float)FS_);
            float y = fminf(fmaxf(yy, 0.0f), (float)(FS_ - 1));
            int y0 = (int)floorf(y);
            int y1i = min(y0 + 1, FS_ - 1);
            float ly = y - (float)y0, hy = 1.0f - ly;
            float qy = vy ? 0.5f : 0.0f;
            float w0 = hy * qy, w1 = ly * qy;
            #pragma unroll
            for (int k = 0; k < FS_; ++k)
                ypro[k] += (k == y0 ? w0 : 0.f) + (k == y1i ? w1 : 0.f);
            // x axis sample s
            float xx = bx.x + ((float)(2 * cww + s) + 0.5f) * 0.5f * bw;
            bool vx = (xx > -1.0f) && (xx < (float)FS_);
            float x = fminf(fmaxf(xx, 0.0f), (float)(FS_ - 1));
            int x0 = (int)floorf(x);
            int x1i = min(x0 + 1, FS_ - 1);
            float lx = x - (float)x0, hx = 1.0f - lx;
            float qx = vx ? 0.5f : 0.0f;
            float u0 = hx * qx, u1 = lx * qx;
            #pragma unroll
            for (int k = 0; k < FS_; ++k)
                xpro[k] += (k == x0 ? u0 : 0.f) + (k == x1i ? u1 : 0.f);
        }
        // write row: 196 products + 36-elem zero pad, packed bf16x2 stores
        __hip_bfloat162* row2 = (__hip_bfloat162*)&Ls[m * SSTR_];
        #pragma unroll
        for (int p = 0; p < 98; ++p) {
            const int i0 = 2 * p, i1 = 2 * p + 1;
            __hip_bfloat162 t;
            t.x = __float2bfloat16(ypro[i0 / FS_] * xpro[i0 % FS_]);
            t.y = __float2bfloat16(ypro[i1 / FS_] * xpro[i1 % FS_]);
            row2[p] = t;
        }
        const __hip_bfloat16 z16 = __float2bfloat16(0.0f);
        #pragma unroll
        for (int p = 98; p < SSTR_ / 2; ++p) {
            __hip_bfloat162 t; t.x = z16; t.y = z16;
            row2[p] = t;
        }
    }

    // ---- phase 0c: convert + write fmap chunk to Bs ----
    #pragma unroll
    for (int it = 0; it < 13; ++it) {
        int i = tid + it * 256;
        if (i < CCH_ * 49) {
            int c = i / 49, ch = i - c * 49;
            float4 v = vbuf[it];
            bf4s t;
            t.lo.x = __float2bfloat16(v.x); t.lo.y = __float2bfloat16(v.y);
            t.hi.x = __float2bfloat16(v.z); t.hi.y = __float2bfloat16(v.w);
            *(bf4s*)&Ls[AOFF_ + c * SSTR_ + ch * 4] = t;
        }
    }
    // ---- phase 0d: zero Bs k-pad (64 rows x elems 196..231) ----
    {
        #pragma unroll
        for (int it = 0; it < 5; ++it) {
            int i = tid + it * 256;
            if (i < CCH_ * 18) {
                int r = i / 18, kd = i - r * 18;
                *(unsigned int*)&Ls[AOFF_ + r * SSTR_ + 196 + kd * 2] = 0;
            }
        }
    }
    __syncthreads();

    // ---- phase 2: MFMA — each wave owns 16 channels (cols) ----
    const int wave = tid >> 6, lane = tid & 63;
    const int m16 = lane & 15, quad = lane >> 4;
    f32x4 acc[5];
    #pragma unroll
    for (int mt = 0; mt < 5; ++mt) acc[mt] = (f32x4){0.f, 0.f, 0.f, 0.f};

    const int nrow = wave * 16 + m16;   // channel row in Bs
    #pragma unroll
    for (int kk = 0; kk < 7; ++kk) {
        bf16x8 bfv = *(const bf16x8*)&Ls[AOFF_ + nrow * SSTR_ + kk * 32 + quad * 8];
        #pragma unroll
        for (int mt = 0; mt < 5; ++mt) {
            bf16x8 af = *(const bf16x8*)&Ls[(mt * 16 + m16) * SSTR_ + kk * 32 + quad * 8];
            acc[mt] = __builtin_amdgcn_mfma_f32_16x16x32_bf16(af, bfv, acc[mt], 0, 0, 0);
        }
    }

    // ---- epilogue: rows = mt*16 + quad*4 + g (< 72), col = channel ----
    const int col = c0 + wave * 16 + m16;
    #pragma unroll
    for (int mt = 0; mt < 5; ++mt) {
        #pragma unroll
        for (int g = 0; g < 4; ++g) {
            int row = mt * 16 + quad * 4 + g;
            if (row < AROWS_)
                pooled[(size_t)(b * AROWS_ + row) * C_ + col] =
                    __float2bfloat16(acc[mt][g]);
        }
    }
}

// ---------------------------------------------------------------------------
// Kernel 3: pooledgemm — feat = pooled @ Wc^T, fp32 out.
//   M=9216, N=256, K=1024; both operands K-contiguous bf16, gld16 staging.
// ---------------------------------------------------------------------------
__global__ __launch_bounds__(256, 4) void pooledgemm_kernel(
    const __hip_bfloat16* __restrict__ A,    // pooled (9216 x 1024)
    const __hip_bfloat16* __restrict__ Bm,   // Wc (256 x 1024)
    float* __restrict__ Cout)                // feat (9216 x 256) fp32
{
    const int tid = threadIdx.x;
    const int wave = tid >> 6, lane = tid & 63;
    const int r0 = blockIdx.y * 64, n0 = blockIdx.x * 64;
    const int wm = (wave >> 1) * 32, wn = (wave & 1) * 32;
    const int m16 = lane & 15, quad = lane >> 4;
    const int K = C_;
    __shared__ __align__(16) __hip_bfloat16 As[64 * 64];
    __shared__ __align__(16) __hip_bfloat16 Bs[64 * 64];

    f32x4 acc[2][2];
    #pragma unroll
    for (int i = 0; i < 2; ++i)
        #pragma unroll
        for (int j = 0; j < 2; ++j)
            acc[i][j] = (f32x4){0.f, 0.f, 0.f, 0.f};

    const int qa = wave * 64 + lane;                 // 0..255
    const int ms0 = qa >> 3, cs0 = (qa & 7) ^ (ms0 & 7);
    const int qb1 = qa + 256;
    const int ms1 = qb1 >> 3, cs1 = (qb1 & 7) ^ (ms1 & 7);
    const size_t rA0 = (size_t)(r0 + ms0) * K + cs0 * 8;
    const size_t rA1 = (size_t)(r0 + ms1) * K + cs1 * 8;
    const size_t rB0 = (size_t)(n0 + ms0) * K + cs0 * 8;
    const size_t rB1 = (size_t)(n0 + ms1) * K + cs1 * 8;

    for (int k0 = 0; k0 < K; k0 += 64) {
        gld16(A  + rA0 + k0, &As[wave * 512]);
        gld16(Bm + rB0 + k0, &Bs[wave * 512]);
        gld16(A  + rA1 + k0, &As[2048 + wave * 512]);
        gld16(Bm + rB1 + k0, &Bs[2048 + wave * 512]);
        __syncthreads();
        #pragma unroll
        for (int ks = 0; ks < 2; ++ks) {
            bf16x8 af[2], bfv[2];
            #pragma unroll
            for (int t = 0; t < 2; ++t) {
                int m = wm + t * 16 + m16;
                int cp = (ks * 4 + quad) ^ (m & 7);
                af[t] = *(const bf16x8*)&As[(m * 8 + cp) * 8];
                int n = wn + t * 16 + m16;
                int cq = (ks * 4 + quad) ^ (n & 7);
                bfv[t] = *(const bf16x8*)&Bs[(n * 8 + cq) * 8];
            }
            #pragma unroll
            for (int i = 0; i < 2; ++i)
                #pragma unroll
                for (int j = 0; j < 2; ++j)
                    acc[i][j] = __builtin_amdgcn_mfma_f32_16x16x32_bf16(
                        af[i], bfv[j], acc[i][j], 0, 0, 0);
        }
        __syncthreads();
    }

    #pragma unroll
    for (int i = 0; i < 2; ++i) {
        #pragma unroll
        for (int j = 0; j < 2; ++j) {
            int col = n0 + wn + j * 16 + m16;
            int rbase = r0 + wm + i * 16 + quad * 4;
            #pragma unroll
            for (int g = 0; g < 4; ++g)
                Cout[(size_t)(rbase + g) * 256 + col] = acc[i][j][g];
        }
    }
}

// ---------------------------------------------------------------------------
// MFMA GEMM (fc1): h1 = relu(diff @ fc1_wp^T + b). 32x64 tile, BK=64.
// ---------------------------------------------------------------------------
__global__ __launch_bounds__(256, 4) void fc1_gemm_kernel(
    const __hip_bfloat16* __restrict__ A,    // diff (1024 x 2304)
    const __hip_bfloat16* __restrict__ Bm,   // fc1_wp (1024 x 2304)
    const float* __restrict__ bias,
    float* __restrict__ C)                   // h1 (1024 x 1024)
{
    const int tid = threadIdx.x;
    const int wave = tid >> 6, lane = tid & 63;
    const int r0 = blockIdx.y * 32, n0 = blockIdx.x * 64;
    const int wm = (wave >> 1) * 16, wn = (wave & 1) * 32;
    const int m16 = lane & 15, quad = lane >> 4;
    const int K = FEATD_;
    __shared__ __align__(16) __hip_bfloat16 As[32 * 64];
    __shared__ __align__(16) __hip_bfloat16 Bs[64 * 64];

    f32x4 acc[2];
    acc[0] = (f32x4){0.f, 0.f, 0.f, 0.f};
    acc[1] = (f32x4){0.f, 0.f, 0.f, 0.f};

    const int qa = wave * 64 + lane;                 // 0..255
    const int msA = qa >> 3, csA = (qa & 7) ^ (msA & 7);
    const int qb1 = qa + 256;
    const int msB1 = qb1 >> 3, csB1 = (qb1 & 7) ^ (msB1 & 7);
    const size_t rA  = (size_t)(r0 + msA)  * K + csA  * 8;
    const size_t rB0 = (size_t)(n0 + msA)  * K + csA  * 8;
    const size_t rB1 = (size_t)(n0 + msB1) * K + csB1 * 8;

    for (int k0 = 0; k0 < K; k0 += 64) {
        gld16(A  + rA  + k0, &As[wave * 512]);
        gld16(Bm + rB0 + k0, &Bs[wave * 512]);
        gld16(Bm + rB1 + k0, &Bs[2048 + wave * 512]);
        __syncthreads();
        #pragma unroll
        for (int ks = 0; ks < 2; ++ks) {
            bf16x8 af, bfv[2];
            int m = wm + m16;
            int cp = (ks * 4 + quad) ^ (m & 7);
            af = *(const bf16x8*)&As[(m * 8 + cp) * 8];
            #pragma unroll
            for (int t = 0; t < 2; ++t) {
                int n = wn + t * 16 + m16;
                int cq = (ks * 4 + quad) ^ (n & 7);
                bfv[t] = *(const bf16x8*)&Bs[(n * 8 + cq) * 8];
            }
            #pragma unroll
            for (int j = 0; j < 2; ++j)
                acc[j] = __builtin_amdgcn_mfma_f32_16x16x32_bf16(
                    af, bfv[j], acc[j], 0, 0, 0);
        }
        __syncthreads();
    }

    #pragma unroll
    for (int j = 0; j < 2; ++j) {
        int col = n0 + wn + j * 16 + m16;
        int rbase = r0 + wm + quad * 4;
        float bv = bias[col];
        #pragma unroll
        for (int g = 0; g < 4; ++g) {
            int r = rbase + g;
            float v = acc[j][g] + bv;
            C[(size_t)r * H1_ + col] = v > 0.f ? v : 0.f;
        }
    }
}

// ---------------------------------------------------------------------------
// fc1_w (1024 x 2304 fp32, k = o*9+hw) -> bf16 permuted (k' = hw*256+o)
// ---------------------------------------------------------------------------
__global__ __launch_bounds__(256) void fc1w_perm_kernel(
    const float* __restrict__ src, __hip_bfloat16* __restrict__ dst)
{
    int h = blockIdx.x;
    int tid = threadIdx.x;
    __shared__ float buf[FEATD_];
    const float* s = src + (size_t)h * FEATD_;
    #pragma unroll
    for (int it = 0; it < 9; ++it)
        buf[it * 256 + tid] = s[it * 256 + tid];
    __syncthreads();
    __hip_bfloat16* d = dst + (size_t)h * FEATD_;
    #pragma unroll
    for (int it = 0; it < 9; ++it) {
        int dd = it * 256 + tid;       // hw = it, o = tid
        d[dd] = __float2bfloat16(buf[tid * HWC_ + it]);
    }
}

// ---------------------------------------------------------------------------
// inv[b][p] = n with pids[b][n]==p else -1
// ---------------------------------------------------------------------------
__global__ __launch_bounds__(64) void invmap_kernel(
    const int* __restrict__ pids, int* __restrict__ inv)
{
    int b = blockIdx.x;
    int p = threadIdx.x;
    if (p < P_) {
        int v = -1;
        for (int n = 0; n < N_; ++n)
            if (pids[b * N_ + n] == p) v = n;
        inv[b * P_ + p] = v;
    }
}

// ---------------------------------------------------------------------------
// meandiff (FUSED meanb+diff): mean kept in registers, feat re-read (L2-hot)
// ---------------------------------------------------------------------------
__global__ __launch_bounds__(256) void meandiff_kernel(
    const float* __restrict__ feat, const int* __restrict__ inv,
    __hip_bfloat16* __restrict__ diff)
{
    int p = blockIdx.x;
    int d = blockIdx.y * 256 + threadIdx.x;
    float acc = 0.0f;
    #pragma unroll 4
    for (int b = 0; b < B_; ++b) {
        int n = inv[b * P_ + p];
        if (n >= 0) acc += feat[(size_t)(b * N_ + n) * FEATD_ + d];
    }
    float mean = acc * (1.0f / (float)B_);
    #pragma unroll 4
    for (int b = 0; b < B_; ++b) {
        int n = inv[b * P_ + p];
        if (n >= 0) {
            size_t r = (size_t)(b * N_ + n);
            diff[r * FEATD_ + d] = __float2bfloat16(mean - feat[r * FEATD_ + d]);
        }
    }
}

// ---------------------------------------------------------------------------
// fc2: out[bn][o] = h1[bn] . fc2_w[o] + fc2_b[o]
// ---------------------------------------------------------------------------
__global__ __launch_bounds__(256) void fc2_kernel(
    const float* __restrict__ h1, const float* __restrict__ fc2_w,
    const float* __restrict__ fc2_b, float* __restrict__ out)
{
    int bn = blockIdx.x;
    int tid = threadIdx.x;
    __shared__ __align__(16) float row[H1_];
    __shared__ float partial[32][8];
    ((float4*)row)[tid] = ((const float4*)(h1 + (size_t)bn * H1_))[tid];
    __syncthreads();
    int o = tid >> 3, part = tid & 7;
    float acc = 0.0f;
    if (o < O_) {
        const float* wrow = fc2_w + (size_t)o * H1_ + part * 128;
        const float* hrow = row + part * 128;
        #pragma unroll 4
        for (int j = 0; j < 128; ++j) acc += hrow[j] * wrow[j];
    }
    partial[o][part] = acc;
    __syncthreads();
    if (part == 0 && o < O_) {
        float s = fc2_b[o];
        #pragma unroll
        for (int p = 0; p < 8; ++p) s += partial[o][p];
        out[(size_t)bn * O_ + o] = s;
    }
}

// ---------------------------------------------------------------------------
// Launch
// ---------------------------------------------------------------------------
extern "C" void kernel_launch(void* const* d_in, const int* in_sizes, int n_in,
                              void* d_out, int out_size, void* d_ws, size_t ws_size,
                              hipStream_t stream) {
    const float* fmap  = (const float*)d_in[0];
    const float* boxes = (const float*)d_in[1];
    const int*   pids  = (const int*)  d_in[2];
    const float* w1    = (const float*)d_in[3];
    const float* w2    = (const float*)d_in[4];
    const float* fc1_w = (const float*)d_in[5];
    const float* fc1_b = (const float*)d_in[6];
    const float* fc2_w = (const float*)d_in[7];
    const float* fc2_b = (const float*)d_in[8];
    float* out = (float*)d_out;

    // workspace layout (all 16B aligned; mean_b slot retained but unused)
    char* wsb = (char*)d_ws;
    __hip_bfloat16* Wc     = (__hip_bfloat16*)wsb;                      // 256*1024
    __hip_bfloat16* pooled = Wc + 256 * 1024;                           // 9216*1024
    __hip_bfloat16* fc1wp  = pooled + (size_t)PROWS_ * C_;              // 1024*2304
    __hip_bfloat16* diffp  = fc1wp + (size_t)H1_ * FEATD_;              // 1024*2304
    float* feat   = (float*)(diffp + (size_t)H1_ * FEATD_);             // 1024*2304
    float* mean_b = feat + (size_t)(B_ * N_) * FEATD_;                  // 20*2304 (unused)
    float* h1     = mean_b + (size_t)P_ * FEATD_;                       // 1024*1024
    int*   inv    = (int*)(h1 + (size_t)(B_ * N_) * H1_);               // 128*20
    float* wpart  = (float*)(inv + 128 * P_ + 64);                      // 8*256*1024

    hipLaunchKernelGGL(wcombine_split_kernel, dim3(16, 4, 8), dim3(256), 0, stream,
                       w1, w2, wpart);
    hipLaunchKernelGGL(wc_reduce_kernel, dim3(1024), dim3(256), 0, stream,
                       wpart, Wc);
    hipLaunchKernelGGL(roipool_kernel, dim3(C_ / CCH_, 128), dim3(256), 0, stream,
                       fmap, boxes, pooled);
    hipLaunchKernelGGL(pooledgemm_kernel, dim3(4, 144), dim3(256), 0, stream,
                       pooled, Wc, feat);
    hipLaunchKernelGGL(fc1w_perm_kernel, dim3(1024), dim3(256), 0, stream,
                       fc1_w, fc1wp);
    hipLaunchKernelGGL(invmap_kernel, dim3(128), dim3(64), 0, stream,
                       pids, inv);
    hipLaunchKernelGGL(meandiff_kernel, dim3(20, 9), dim3(256), 0, stream,
                       feat, inv, diffp);
    hipLaunchKernelGGL(fc1_gemm_kernel, dim3(16, 32), dim3(256), 0, stream,
                       diffp, fc1wp, fc1_b, h1);
    hipLaunchKernelGGL(fc2_kernel, dim3(1024), dim3(256), 0, stream,
                       h1, fc2_w, fc2_b, out);
}

// Round 10
// 297.874 us; speedup vs baseline: 1.0184x; 1.0184x over previous
//
#include <hip/hip_runtime.h>
#include <hip/hip_bf16.h>
#include <cstddef>
#include <cstdint>

// ---------------------------------------------------------------------------
// Problem constants
// ---------------------------------------------------------------------------
#define B_   128
#define N_   8
#define C_   1024
#define FS_  14
#define POS_ 196            // 14*14
#define P_   20
#define HWC_ 9              // 3*3 cells
#define CMID_ 256
#define FEATD_ 2304         // CMID*HWC
#define H1_  1024
#define O_   27

typedef __attribute__((ext_vector_type(8))) short bf16x8;   // 8 bf16 (4 VGPRs)
typedef __attribute__((ext_vector_type(4))) float f32x4;

// async global->LDS, 16B per lane; LDS dest = wave-uniform base + lane*16
__device__ __forceinline__ void gld16(const void* g, void* l) {
    __builtin_amdgcn_global_load_lds(
        (const __attribute__((address_space(1))) unsigned int*)g,
        (__attribute__((address_space(3))) unsigned int*)l, 16, 0, 0);
}

// ---------------------------------------------------------------------------
// Kernel 1a: split-K partials of Wc = w2 @ w1
// ---------------------------------------------------------------------------
__global__ __launch_bounds__(256) void wcombine_split_kernel(
    const float* __restrict__ w1,   // (512,1024)
    const float* __restrict__ w2,   // (256,512)
    float* __restrict__ wpart)      // (8,256,1024) fp32
{
    const int tid = threadIdx.x;
    const int tx = tid & 15, ty = tid >> 4;
    const int c0 = blockIdx.x * 64;
    const int o0 = blockIdx.y * 64;
    const int kb = blockIdx.z * 64;
    __shared__ __align__(16) float As[16][68];
    __shared__ __align__(16) float Bs[16][68];
    float acc[4][4] = {};
    for (int k0 = kb; k0 < kb + 64; k0 += 16) {
        for (int i = tid; i < 64 * 16; i += 256) {
            int k = i & 15, m = i >> 4;
            As[k][m] = w2[(size_t)(o0 + m) * 512 + k0 + k];
        }
        for (int i = tid; i < 64 * 16; i += 256) {
            int n = i & 63, k = i >> 6;
            Bs[k][n] = w1[(size_t)(k0 + k) * 1024 + c0 + n];
        }
        __syncthreads();
        #pragma unroll
        for (int k = 0; k < 16; ++k) {
            float4 a = *(const float4*)&As[k][ty * 4];
            float4 b = *(const float4*)&Bs[k][tx * 4];
            float av[4] = {a.x, a.y, a.z, a.w};
            float bv[4] = {b.x, b.y, b.z, b.w};
            #pragma unroll
            for (int i = 0; i < 4; ++i)
                #pragma unroll
                for (int j = 0; j < 4; ++j)
                    acc[i][j] += av[i] * bv[j];
        }
        __syncthreads();
    }
    float* dst = wpart + (size_t)blockIdx.z * (256 * 1024);
    for (int i = 0; i < 4; ++i) {
        float4 v = make_float4(acc[i][0], acc[i][1], acc[i][2], acc[i][3]);
        *(float4*)&dst[(size_t)(o0 + ty * 4 + i) * 1024 + c0 + tx * 4] = v;
    }
}

// ---------------------------------------------------------------------------
// Kernel 1b: Wc = bf16( sum_z wpart[z] )
// ---------------------------------------------------------------------------
__global__ __launch_bounds__(256) void wc_reduce_kernel(
    const float* __restrict__ wpart, __hip_bfloat16* __restrict__ Wc)
{
    int idx = blockIdx.x * 256 + threadIdx.x;
    float s = 0.f;
    #pragma unroll
    for (int z = 0; z < 8; ++z) s += wpart[(size_t)z * (256 * 1024) + idx];
    Wc[idx] = __float2bfloat16(s);
}

// ---------------------------------------------------------------------------
// Kernel 2 (FUSED): poolmix — feat_part[cq][b] (72x256) =
//     (Wpool[b] (72x196) @ fmap[b, cq-half]^T) @ Wc[:, cq-half]^T
//   R9 post-mortem: 3 roipool micro-fixes changed nothing -> the cost was
//   the stage->barrier->tiny-MFMA streaming structure + the pooled 18MB
//   round-trip + pooledgemm itself. This kernel streams fmap ONCE and
//   never materializes pooled:
//   grid (2 cq, 128 b), 256 thr. Per block:
//     - build Wpool A-tile (72x232 bf16) once (R9's separable build, which
//       passed refcheck); A k-pad 196..231 is zero -> Bs pad may be garbage
//       EXCEPT NaN, so Bs pad zeroed once in prologue.
//     - loop 8 chunks of 64 channels:
//         stage fmap chunk -> Bs (fp32->bf16, coalesced float4)
//         barrier
//         MFMA1: pooled_chunk(72x64) = A @ Bs^T  (R9 phase-2 mapping)
//         write Ps (72 rows, stride 72 -> 2-way bank alias only; rows 72..79
//           unwritten: their garbage only feeds discarded D-rows)
//         barrier
//         MFMA2: acc2(72x256 fp32, 80 VGPR) += Ps @ WcChunk^T; B-fragments
//           loaded DIRECTLY from L2-resident Wc (512KB shared by all blocks)
//     - epilogue: featp[cq] (same flat layout as feat) <- acc2.
//   Rounding path identical to R8/R9+pooledgemm (bf16 quantization of
//   pooled at the same point, fp32 K-accum in the same chunk order).
//   LDS: A 33.4K + Bs 29.7K + Ps 10.4K = 71.8 KB -> 2 blocks/CU.
// ---------------------------------------------------------------------------
#define SSTR_  232            // A/Bs row stride in bf16 (16B-aligned rows)
#define AROWS_ 72
#define BOFF_  (AROWS_ * SSTR_)        // Bs base (elems)
#define PSTR_  72                      // Ps row stride (144B: 2-way alias)
#define POFF_  (BOFF_ + 64 * SSTR_)    // Ps base (elems)
struct bf4s { __hip_bfloat162 lo, hi; };
__global__ __launch_bounds__(256, 2) void poolmix_kernel(
    const float* __restrict__ fmap,          // (128,1024,196)
    const float* __restrict__ boxes,         // (128,8,4)
    const __hip_bfloat16* __restrict__ Wc,   // (256,1024)
    float* __restrict__ featp)               // (2, 128*72, 256) fp32
{
    const int cq = blockIdx.x;               // channel half 0/1
    const int b  = blockIdx.y;
    const int tid = threadIdx.x;
    const int wave = tid >> 6, lane = tid & 63;
    const int m16 = lane & 15, quad = lane >> 4;
    __shared__ __align__(16) __hip_bfloat16 Ls[POFF_ + AROWS_ * PSTR_];

    // ---- prologue A: build Wpool rows (separable outer product) ----
    if (tid < AROWS_) {
        const int m = tid;
        const int n = m / 9, cell = m - n * 9;
        const int chh = cell / 3, cww = cell % 3;
        float4 bx = *(const float4*)(boxes + ((size_t)b * N_ + n) * 4);
        float bw = (bx.z - bx.x) * (1.0f / 3.0f);
        float bh = (bx.w - bx.y) * (1.0f / 3.0f);
        float ypro[FS_], xpro[FS_];
        #pragma unroll
        for (int k = 0; k < FS_; ++k) { ypro[k] = 0.f; xpro[k] = 0.f; }
        #pragma unroll
        for (int s = 0; s < 2; ++s) {
            float yy = bx.y + ((float)(2 * chh + s) + 0.5f) * 0.5f * bh;
            bool vy = (yy > -1.0f) && (yy < (float)FS_);
            float y = fminf(fmaxf(yy, 0.0f), (float)(FS_ - 1));
            int y0 = (int)floorf(y);
            int y1i = min(y0 + 1, FS_ - 1);
            float ly = y - (float)y0, hy = 1.0f - ly;
            float qy = vy ? 0.5f : 0.0f;
            float w0 = hy * qy, w1 = ly * qy;
            #pragma unroll
            for (int k = 0; k < FS_; ++k)
                ypro[k] += (k == y0 ? w0 : 0.f) + (k == y1i ? w1 : 0.f);
            float xx = bx.x + ((float)(2 * cww + s) + 0.5f) * 0.5f * bw;
            bool vx = (xx > -1.0f) && (xx < (float)FS_);
            float x = fminf(fmaxf(xx, 0.0f), (float)(FS_ - 1));
            int x0 = (int)floorf(x);
            int x1i = min(x0 + 1, FS_ - 1);
            float lx = x - (float)x0, hx = 1.0f - lx;
            float qx = vx ? 0.5f : 0.0f;
            float u0 = hx * qx, u1 = lx * qx;
            #pragma unroll
            for (int k = 0; k < FS_; ++k)
                xpro[k] += (k == x0 ? u0 : 0.f) + (k == x1i ? u1 : 0.f);
        }
        __hip_bfloat162* row2 = (__hip_bfloat162*)&Ls[m * SSTR_];
        #pragma unroll
        for (int p = 0; p < 98; ++p) {
            const int i0 = 2 * p, i1 = 2 * p + 1;
            __hip_bfloat162 t;
            t.x = __float2bfloat16(ypro[i0 / FS_] * xpro[i0 % FS_]);
            t.y = __float2bfloat16(ypro[i1 / FS_] * xpro[i1 % FS_]);
            row2[p] = t;
        }
        const __hip_bfloat16 z16 = __float2bfloat16(0.0f);
        #pragma unroll
        for (int p = 98; p < SSTR_ / 2; ++p) {
            __hip_bfloat162 t; t.x = z16; t.y = z16;
            row2[p] = t;
        }
    }
    // ---- prologue B: zero Bs k-pad once (guards against NaN garbage) ----
    for (int i = tid; i < 64 * 18; i += 256) {
        int r = i / 18, kd = i - r * 18;
        *(unsigned int*)&Ls[BOFF_ + r * SSTR_ + 196 + kd * 2] = 0;
    }

    // persistent output accumulator: wave owns cols [wave*64, wave*64+64)
    f32x4 acc2[5][4];
    #pragma unroll
    for (int mt = 0; mt < 5; ++mt)
        #pragma unroll
        for (int nt = 0; nt < 4; ++nt)
            acc2[mt][nt] = (f32x4){0.f, 0.f, 0.f, 0.f};

    const int cbase0 = cq * 512;
    for (int c = 0; c < 8; ++c) {
        // ---- stage fmap chunk (64 channels x 196 pos) fp32->bf16 ----
        const float* src = fmap + ((size_t)b * C_ + cbase0 + c * 64) * POS_;
        #pragma unroll
        for (int it = 0; it < 13; ++it) {
            int i = tid + it * 256;
            if (i < 64 * 49) {
                int cr = i / 49, ch = i - cr * 49;
                float4 v = *(const float4*)(src + (size_t)cr * POS_ + ch * 4);
                bf4s t;
                t.lo.x = __float2bfloat16(v.x); t.lo.y = __float2bfloat16(v.y);
                t.hi.x = __float2bfloat16(v.z); t.hi.y = __float2bfloat16(v.w);
                *(bf4s*)&Ls[BOFF_ + cr * SSTR_ + ch * 4] = t;
            }
        }
        __syncthreads();   // Bs ready (and A ready on c=0; Ps free: all
                           // waves finished MFMA2(c-1) before this point)

        // ---- MFMA1: pooled_chunk(72x64) = A @ Bs^T ----
        f32x4 acc1[5];
        #pragma unroll
        for (int mt = 0; mt < 5; ++mt) acc1[mt] = (f32x4){0.f, 0.f, 0.f, 0.f};
        const int nrow = wave * 16 + m16;    // channel within chunk
        #pragma unroll
        for (int kk = 0; kk < 7; ++kk) {
            bf16x8 bfv = *(const bf16x8*)&Ls[BOFF_ + nrow * SSTR_ + kk * 32 + quad * 8];
            #pragma unroll
            for (int mt = 0; mt < 5; ++mt) {
                bf16x8 af = *(const bf16x8*)&Ls[(mt * 16 + m16) * SSTR_ + kk * 32 + quad * 8];
                acc1[mt] = __builtin_amdgcn_mfma_f32_16x16x32_bf16(af, bfv, acc1[mt], 0, 0, 0);
            }
        }
        // ---- write Ps[cell][chan] (bf16) ----
        #pragma unroll
        for (int mt = 0; mt < 5; ++mt) {
            #pragma unroll
            for (int g = 0; g < 4; ++g) {
                int cell = mt * 16 + quad * 4 + g;
                if (cell < AROWS_)
                    Ls[POFF_ + cell * PSTR_ + wave * 16 + m16] =
                        __float2bfloat16(acc1[mt][g]);
            }
        }
        __syncthreads();   // Ps ready; Bs free for next stage (MFMA2 below
                           // reads only Ps + global Wc)

        // ---- MFMA2: acc2 += Ps(72x64) @ WcChunk(256x64)^T ----
        #pragma unroll
        for (int ks = 0; ks < 2; ++ks) {
            bf16x8 af[5];
            #pragma unroll
            for (int mt = 0; mt < 5; ++mt)
                af[mt] = *(const bf16x8*)&Ls[POFF_ + (mt * 16 + m16) * PSTR_ + ks * 32 + quad * 8];
            #pragma unroll
            for (int nt = 0; nt < 4; ++nt) {
                int n = wave * 64 + nt * 16 + m16;
                bf16x8 bfv = *(const bf16x8*)(Wc + (size_t)n * C_ + cbase0 + c * 64 + ks * 32 + quad * 8);
                #pragma unroll
                for (int mt = 0; mt < 5; ++mt)
                    acc2[mt][nt] = __builtin_amdgcn_mfma_f32_16x16x32_bf16(
                        af[mt], bfv, acc2[mt][nt], 0, 0, 0);
            }
        }
    }

    // ---- epilogue: featp[cq][(b*72+row)*256 + col] ----
    float* dst = featp + (size_t)cq * (128 * AROWS_ * 256);
    #pragma unroll
    for (int mt = 0; mt < 5; ++mt) {
        #pragma unroll
        for (int g = 0; g < 4; ++g) {
            int row = mt * 16 + quad * 4 + g;
            if (row < AROWS_) {
                #pragma unroll
                for (int nt = 0; nt < 4; ++nt)
                    dst[(size_t)(b * AROWS_ + row) * 256 + wave * 64 + nt * 16 + m16] =
                        acc2[mt][nt][g];
            }
        }
    }
}

// ---------------------------------------------------------------------------
// MFMA GEMM (fc1): h1 = relu(diff @ fc1_wp^T + b). 32x64 tile, BK=64.
// ---------------------------------------------------------------------------
__global__ __launch_bounds__(256, 4) void fc1_gemm_kernel(
    const __hip_bfloat16* __restrict__ A,    // diff (1024 x 2304)
    const __hip_bfloat16* __restrict__ Bm,   // fc1_wp (1024 x 2304)
    const float* __restrict__ bias,
    float* __restrict__ C)                   // h1 (1024 x 1024)
{
    const int tid = threadIdx.x;
    const int wave = tid >> 6, lane = tid & 63;
    const int r0 = blockIdx.y * 32, n0 = blockIdx.x * 64;
    const int wm = (wave >> 1) * 16, wn = (wave & 1) * 32;
    const int m16 = lane & 15, quad = lane >> 4;
    const int K = FEATD_;
    __shared__ __align__(16) __hip_bfloat16 As[32 * 64];
    __shared__ __align__(16) __hip_bfloat16 Bs[64 * 64];

    f32x4 acc[2];
    acc[0] = (f32x4){0.f, 0.f, 0.f, 0.f};
    acc[1] = (f32x4){0.f, 0.f, 0.f, 0.f};

    const int qa = wave * 64 + lane;                 // 0..255
    const int msA = qa >> 3, csA = (qa & 7) ^ (msA & 7);
    const int qb1 = qa + 256;
    const int msB1 = qb1 >> 3, csB1 = (qb1 & 7) ^ (msB1 & 7);
    const size_t rA  = (size_t)(r0 + msA)  * K + csA  * 8;
    const size_t rB0 = (size_t)(n0 + msA)  * K + csA  * 8;
    const size_t rB1 = (size_t)(n0 + msB1) * K + csB1 * 8;

    for (int k0 = 0; k0 < K; k0 += 64) {
        gld16(A  + rA  + k0, &As[wave * 512]);
        gld16(Bm + rB0 + k0, &Bs[wave * 512]);
        gld16(Bm + rB1 + k0, &Bs[2048 + wave * 512]);
        __syncthreads();
        #pragma unroll
        for (int ks = 0; ks < 2; ++ks) {
            bf16x8 af, bfv[2];
            int m = wm + m16;
            int cp = (ks * 4 + quad) ^ (m & 7);
            af = *(const bf16x8*)&As[(m * 8 + cp) * 8];
            #pragma unroll
            for (int t = 0; t < 2; ++t) {
                int n = wn + t * 16 + m16;
                int cq = (ks * 4 + quad) ^ (n & 7);
                bfv[t] = *(const bf16x8*)&Bs[(n * 8 + cq) * 8];
            }
            #pragma unroll
            for (int j = 0; j < 2; ++j)
                acc[j] = __builtin_amdgcn_mfma_f32_16x16x32_bf16(
                    af, bfv[j], acc[j], 0, 0, 0);
        }
        __syncthreads();
    }

    #pragma unroll
    for (int j = 0; j < 2; ++j) {
        int col = n0 + wn + j * 16 + m16;
        int rbase = r0 + wm + quad * 4;
        float bv = bias[col];
        #pragma unroll
        for (int g = 0; g < 4; ++g) {
            int r = rbase + g;
            float v = acc[j][g] + bv;
            C[(size_t)r * H1_ + col] = v > 0.f ? v : 0.f;
        }
    }
}

// ---------------------------------------------------------------------------
// fc1_w (1024 x 2304 fp32, k = o*9+hw) -> bf16 permuted (k' = hw*256+o)
// ---------------------------------------------------------------------------
__global__ __launch_bounds__(256) void fc1w_perm_kernel(
    const float* __restrict__ src, __hip_bfloat16* __restrict__ dst)
{
    int h = blockIdx.x;
    int tid = threadIdx.x;
    __shared__ float buf[FEATD_];
    const float* s = src + (size_t)h * FEATD_;
    #pragma unroll
    for (int it = 0; it < 9; ++it)
        buf[it * 256 + tid] = s[it * 256 + tid];
    __syncthreads();
    __hip_bfloat16* d = dst + (size_t)h * FEATD_;
    #pragma unroll
    for (int it = 0; it < 9; ++it) {
        int dd = it * 256 + tid;       // hw = it, o = tid
        d[dd] = __float2bfloat16(buf[tid * HWC_ + it]);
    }
}

// ---------------------------------------------------------------------------
// meandiff (FUSED invmap+meanb+diff): feat = fp0 + fp1 (elementwise, same
//   flat layout as before). inv computed per block from pids (wave-uniform
//   scan -> LDS). mean kept in registers; diff written bf16.
// ---------------------------------------------------------------------------
__global__ __launch_bounds__(256) void meandiff_kernel(
    const float* __restrict__ fp0, const float* __restrict__ fp1,
    const int* __restrict__ pids, __hip_bfloat16* __restrict__ diff)
{
    int p = blockIdx.x;
    int d = blockIdx.y * 256 + threadIdx.x;
    __shared__ int invs[B_];
    if (threadIdx.x < B_) {
        int bb = threadIdx.x;
        int v = -1;
        #pragma unroll
        for (int n = 0; n < N_; ++n)
            if (pids[bb * N_ + n] == p) v = n;
        invs[bb] = v;
    }
    __syncthreads();

    float acc = 0.0f;
    #pragma unroll 4
    for (int b = 0; b < B_; ++b) {
        int n = invs[b];
        if (n >= 0) {
            size_t idx = (size_t)(b * N_ + n) * FEATD_ + d;
            acc += fp0[idx] + fp1[idx];
        }
    }
    float mean = acc * (1.0f / (float)B_);
    #pragma unroll 4
    for (int b = 0; b < B_; ++b) {
        int n = invs[b];
        if (n >= 0) {
            size_t idx = (size_t)(b * N_ + n) * FEATD_ + d;
            diff[idx] = __float2bfloat16(mean - (fp0[idx] + fp1[idx]));
        }
    }
}

// ---------------------------------------------------------------------------
// fc2: out[bn][o] = h1[bn] . fc2_w[o] + fc2_b[o]
// ---------------------------------------------------------------------------
__global__ __launch_bounds__(256) void fc2_kernel(
    const float* __restrict__ h1, const float* __restrict__ fc2_w,
    const float* __restrict__ fc2_b, float* __restrict__ out)
{
    int bn = blockIdx.x;
    int tid = threadIdx.x;
    __shared__ __align__(16) float row[H1_];
    __shared__ float partial[32][8];
    ((float4*)row)[tid] = ((const float4*)(h1 + (size_t)bn * H1_))[tid];
    __syncthreads();
    int o = tid >> 3, part = tid & 7;
    float acc = 0.0f;
    if (o < O_) {
        const float* wrow = fc2_w + (size_t)o * H1_ + part * 128;
        const float* hrow = row + part * 128;
        #pragma unroll 4
        for (int j = 0; j < 128; ++j) acc += hrow[j] * wrow[j];
    }
    partial[o][part] = acc;
    __syncthreads();
    if (part == 0 && o < O_) {
        float s = fc2_b[o];
        #pragma unroll
        for (int p = 0; p < 8; ++p) s += partial[o][p];
        out[(size_t)bn * O_ + o] = s;
    }
}

// ---------------------------------------------------------------------------
// Launch
// ---------------------------------------------------------------------------
extern "C" void kernel_launch(void* const* d_in, const int* in_sizes, int n_in,
                              void* d_out, int out_size, void* d_ws, size_t ws_size,
                              hipStream_t stream) {
    const float* fmap  = (const float*)d_in[0];
    const float* boxes = (const float*)d_in[1];
    const int*   pids  = (const int*)  d_in[2];
    const float* w1    = (const float*)d_in[3];
    const float* w2    = (const float*)d_in[4];
    const float* fc1_w = (const float*)d_in[5];
    const float* fc1_b = (const float*)d_in[6];
    const float* fc2_w = (const float*)d_in[7];
    const float* fc2_b = (const float*)d_in[8];
    float* out = (float*)d_out;

    // workspace layout (all 16B aligned)
    char* wsb = (char*)d_ws;
    __hip_bfloat16* Wc    = (__hip_bfloat16*)wsb;                       // 256*1024
    __hip_bfloat16* fc1wp = Wc + 256 * 1024;                            // 1024*2304
    __hip_bfloat16* diffp = fc1wp + (size_t)H1_ * FEATD_;               // 1024*2304
    float* featp  = (float*)(diffp + (size_t)H1_ * FEATD_);             // 2*1024*2304
    float* h1     = featp + 2 * (size_t)(B_ * N_) * FEATD_;             // 1024*1024
    float* wpart  = h1 + (size_t)(B_ * N_) * H1_;                       // 8*256*1024
    float* fp0 = featp;
    float* fp1 = featp + (size_t)(B_ * N_) * FEATD_;

    hipLaunchKernelGGL(wcombine_split_kernel, dim3(16, 4, 8), dim3(256), 0, stream,
                       w1, w2, wpart);
    hipLaunchKernelGGL(wc_reduce_kernel, dim3(1024), dim3(256), 0, stream,
                       wpart, Wc);
    hipLaunchKernelGGL(poolmix_kernel, dim3(2, 128), dim3(256), 0, stream,
                       fmap, boxes, Wc, featp);
    hipLaunchKernelGGL(fc1w_perm_kernel, dim3(1024), dim3(256), 0, stream,
                       fc1_w, fc1wp);
    hipLaunchKernelGGL(meandiff_kernel, dim3(20, 9), dim3(256), 0, stream,
                       fp0, fp1, pids, diffp);
    hipLaunchKernelGGL(fc1_gemm_kernel, dim3(16, 32), dim3(256), 0, stream,
                       diffp, fc1wp, fc1_b, h1);
    hipLaunchKernelGGL(fc2_kernel, dim3(1024), dim3(256), 0, stream,
                       h1, fc2_w, fc2_b, out);
}

// Round 12
// 296.070 us; speedup vs baseline: 1.0246x; 1.0061x over previous
//
#include <hip/hip_runtime.h>
#include <hip/hip_bf16.h>
#include <cstddef>
#include <cstdint>

// ---------------------------------------------------------------------------
// Problem constants
// ---------------------------------------------------------------------------
#define B_   128
#define N_   8
#define C_   1024
#define FS_  14
#define POS_ 196            // 14*14
#define P_   20
#define HWC_ 9              // 3*3 cells
#define CMID_ 256
#define FEATD_ 2304         // CMID*HWC
#define H1_  1024
#define O_   27

typedef __attribute__((ext_vector_type(8))) short bf16x8;   // 8 bf16 (4 VGPRs)
typedef __attribute__((ext_vector_type(4))) float f32x4;

// async global->LDS, 16B per lane; LDS dest = wave-uniform base + lane*16
__device__ __forceinline__ void gld16(const void* g, void* l) {
    __builtin_amdgcn_global_load_lds(
        (const __attribute__((address_space(1))) unsigned int*)g,
        (__attribute__((address_space(3))) unsigned int*)l, 16, 0, 0);
}

// ---------------------------------------------------------------------------
// Kernel 1a: split-K partials of Wc = w2 @ w1
// ---------------------------------------------------------------------------
__global__ __launch_bounds__(256) void wcombine_split_kernel(
    const float* __restrict__ w1,   // (512,1024)
    const float* __restrict__ w2,   // (256,512)
    float* __restrict__ wpart)      // (8,256,1024) fp32
{
    const int tid = threadIdx.x;
    const int tx = tid & 15, ty = tid >> 4;
    const int c0 = blockIdx.x * 64;
    const int o0 = blockIdx.y * 64;
    const int kb = blockIdx.z * 64;
    __shared__ __align__(16) float As[16][68];
    __shared__ __align__(16) float Bs[16][68];
    float acc[4][4] = {};
    for (int k0 = kb; k0 < kb + 64; k0 += 16) {
        for (int i = tid; i < 64 * 16; i += 256) {
            int k = i & 15, m = i >> 4;
            As[k][m] = w2[(size_t)(o0 + m) * 512 + k0 + k];
        }
        for (int i = tid; i < 64 * 16; i += 256) {
            int n = i & 63, k = i >> 6;
            Bs[k][n] = w1[(size_t)(k0 + k) * 1024 + c0 + n];
        }
        __syncthreads();
        #pragma unroll
        for (int k = 0; k < 16; ++k) {
            float4 a = *(const float4*)&As[k][ty * 4];
            float4 b = *(const float4*)&Bs[k][tx * 4];
            float av[4] = {a.x, a.y, a.z, a.w};
            float bv[4] = {b.x, b.y, b.z, b.w};
            #pragma unroll
            for (int i = 0; i < 4; ++i)
                #pragma unroll
                for (int j = 0; j < 4; ++j)
                    acc[i][j] += av[i] * bv[j];
        }
        __syncthreads();
    }
    float* dst = wpart + (size_t)blockIdx.z * (256 * 1024);
    for (int i = 0; i < 4; ++i) {
        float4 v = make_float4(acc[i][0], acc[i][1], acc[i][2], acc[i][3]);
        *(float4*)&dst[(size_t)(o0 + ty * 4 + i) * 1024 + c0 + tx * 4] = v;
    }
}

// ---------------------------------------------------------------------------
// Kernel 1b: Wc = bf16( sum_z wpart[z] )
// ---------------------------------------------------------------------------
__global__ __launch_bounds__(256) void wc_reduce_kernel(
    const float* __restrict__ wpart, __hip_bfloat16* __restrict__ Wc)
{
    int idx = blockIdx.x * 256 + threadIdx.x;
    float s = 0.f;
    #pragma unroll
    for (int z = 0; z < 8; ++z) s += wpart[(size_t)z * (256 * 1024) + idx];
    Wc[idx] = __float2bfloat16(s);
}

// ---------------------------------------------------------------------------
// Kernel 2 (FUSED): poolmix — feat_part[cq][b] (72x256) =
//     (Wpool[b] (72x196) @ fmap[b, cq-quarter]^T) @ Wc[:, cq-quarter]^T
//   R10 post-mortem: grid (2,128)=256 blocks = exactly 1 block/CU; counters
//   (MfmaUtil 5.3, VALU 4.2, hbm 13%, Occ 10%) -> ~90% stall: the serial
//   stage->barrier->MFMA chunk loop has NOTHING co-resident to hide the
//   ~5000cy/chunk memory wait. Fix:
//   - channel K-split 2 -> 4 quarters: grid (4,128)=512 blocks = 2/CU
//     (LDS 72KB fits 2/CU) -> one block's MFMA overlaps the other's stage.
//   - T14 reg prefetch: chunk c+1's 13 float4 loads issued before MFMA1(c),
//     converted+written to Bs AFTER the Ps-barrier (all waves provably done
//     reading Bs(c)); barrier count per chunk unchanged (2).
//   featp becomes 4 partial sums (summed in meandiff).
//   Numerics: same rounding points; K-partition reassociation only.
// ---------------------------------------------------------------------------
#define SSTR_  232            // A/Bs row stride in bf16 (16B-aligned rows)
#define AROWS_ 72
#define BOFF_  (AROWS_ * SSTR_)        // Bs base (elems)
#define PSTR_  72                      // Ps row stride (144B: 2-way alias)
#define POFF_  (BOFF_ + 64 * SSTR_)    // Ps base (elems)
#define NCHUNK_ 4                      // 4 x 64 channels per block
struct bf4s { __hip_bfloat162 lo, hi; };
__global__ __launch_bounds__(256, 2) void poolmix_kernel(
    const float* __restrict__ fmap,          // (128,1024,196)
    const float* __restrict__ boxes,         // (128,8,4)
    const __hip_bfloat16* __restrict__ Wc,   // (256,1024)
    float* __restrict__ featp)               // (4, 128*72, 256) fp32
{
    const int cq = blockIdx.x;               // channel quarter 0..3
    const int b  = blockIdx.y;
    const int tid = threadIdx.x;
    const int wave = tid >> 6, lane = tid & 63;
    const int m16 = lane & 15, quad = lane >> 4;
    __shared__ __align__(16) __hip_bfloat16 Ls[POFF_ + AROWS_ * PSTR_];

    // ---- prologue A: build Wpool rows (separable outer product) ----
    if (tid < AROWS_) {
        const int m = tid;
        const int n = m / 9, cell = m - n * 9;
        const int chh = cell / 3, cww = cell % 3;
        float4 bx = *(const float4*)(boxes + ((size_t)b * N_ + n) * 4);
        float bw = (bx.z - bx.x) * (1.0f / 3.0f);
        float bh = (bx.w - bx.y) * (1.0f / 3.0f);
        float ypro[FS_], xpro[FS_];
        #pragma unroll
        for (int k = 0; k < FS_; ++k) { ypro[k] = 0.f; xpro[k] = 0.f; }
        #pragma unroll
        for (int s = 0; s < 2; ++s) {
            float yy = bx.y + ((float)(2 * chh + s) + 0.5f) * 0.5f * bh;
            bool vy = (yy > -1.0f) && (yy < (float)FS_);
            float y = fminf(fmaxf(yy, 0.0f), (float)(FS_ - 1));
            int y0 = (int)floorf(y);
            int y1i = min(y0 + 1, FS_ - 1);
            float ly = y - (float)y0, hy = 1.0f - ly;
            float qy = vy ? 0.5f : 0.0f;
            float w0 = hy * qy, w1 = ly * qy;
            #pragma unroll
            for (int k = 0; k < FS_; ++k)
                ypro[k] += (k == y0 ? w0 : 0.f) + (k == y1i ? w1 : 0.f);
            float xx = bx.x + ((float)(2 * cww + s) + 0.5f) * 0.5f * bw;
            bool vx = (xx > -1.0f) && (xx < (float)FS_);
            float x = fminf(fmaxf(xx, 0.0f), (float)(FS_ - 1));
            int x0 = (int)floorf(x);
            int x1i = min(x0 + 1, FS_ - 1);
            float lx = x - (float)x0, hx = 1.0f - lx;
            float qx = vx ? 0.5f : 0.0f;
            float u0 = hx * qx, u1 = lx * qx;
            #pragma unroll
            for (int k = 0; k < FS_; ++k)
                xpro[k] += (k == x0 ? u0 : 0.f) + (k == x1i ? u1 : 0.f);
        }
        __hip_bfloat162* row2 = (__hip_bfloat162*)&Ls[m * SSTR_];
        #pragma unroll
        for (int p = 0; p < 98; ++p) {
            const int i0 = 2 * p, i1 = 2 * p + 1;
            __hip_bfloat162 t;
            t.x = __float2bfloat16(ypro[i0 / FS_] * xpro[i0 % FS_]);
            t.y = __float2bfloat16(ypro[i1 / FS_] * xpro[i1 % FS_]);
            row2[p] = t;
        }
        const __hip_bfloat16 z16 = __float2bfloat16(0.0f);
        #pragma unroll
        for (int p = 98; p < SSTR_ / 2; ++p) {
            __hip_bfloat162 t; t.x = z16; t.y = z16;
            row2[p] = t;
        }
    }
    // ---- prologue B: zero Bs k-pad once (guards against NaN garbage) ----
    for (int i = tid; i < 64 * 18; i += 256) {
        int r = i / 18, kd = i - r * 18;
        *(unsigned int*)&Ls[BOFF_ + r * SSTR_ + 196 + kd * 2] = 0;
    }
    // ---- prologue C: stage chunk 0 directly ----
    const int cbase0 = cq * 256;
    {
        const float* src = fmap + ((size_t)b * C_ + cbase0) * POS_;
        #pragma unroll
        for (int it = 0; it < 13; ++it) {
            int i = tid + it * 256;
            if (i < 64 * 49) {
                int cr = i / 49, ch = i - cr * 49;
                float4 v = *(const float4*)(src + (size_t)cr * POS_ + ch * 4);
                bf4s t;
                t.lo.x = __float2bfloat16(v.x); t.lo.y = __float2bfloat16(v.y);
                t.hi.x = __float2bfloat16(v.z); t.hi.y = __float2bfloat16(v.w);
                *(bf4s*)&Ls[BOFF_ + cr * SSTR_ + ch * 4] = t;
            }
        }
    }

    // persistent output accumulator: wave owns cols [wave*64, wave*64+64)
    f32x4 acc2[5][4];
    #pragma unroll
    for (int mt = 0; mt < 5; ++mt)
        #pragma unroll
        for (int nt = 0; nt < 4; ++nt)
            acc2[mt][nt] = (f32x4){0.f, 0.f, 0.f, 0.f};

    float4 vbuf[13];
    for (int c = 0; c < NCHUNK_; ++c) {
        __syncthreads();   // Bs(c) visible; all waves done MFMA2(c-1) (Ps free)

        // ---- T14 prefetch: issue chunk c+1 global loads into registers ----
        if (c < NCHUNK_ - 1) {
            const float* src = fmap + ((size_t)b * C_ + cbase0 + (c + 1) * 64) * POS_;
            #pragma unroll
            for (int it = 0; it < 13; ++it) {
                int i = tid + it * 256;
                if (i < 64 * 49) {
                    int cr = i / 49, ch = i - cr * 49;
                    vbuf[it] = *(const float4*)(src + (size_t)cr * POS_ + ch * 4);
                }
            }
        }

        // ---- MFMA1: pooled_chunk(72x64) = A @ Bs^T ----
        f32x4 acc1[5];
        #pragma unroll
        for (int mt = 0; mt < 5; ++mt) acc1[mt] = (f32x4){0.f, 0.f, 0.f, 0.f};
        const int nrow = wave * 16 + m16;    // channel within chunk
        #pragma unroll
        for (int kk = 0; kk < 7; ++kk) {
            bf16x8 bfv = *(const bf16x8*)&Ls[BOFF_ + nrow * SSTR_ + kk * 32 + quad * 8];
            #pragma unroll
            for (int mt = 0; mt < 5; ++mt) {
                bf16x8 af = *(const bf16x8*)&Ls[(mt * 16 + m16) * SSTR_ + kk * 32 + quad * 8];
                acc1[mt] = __builtin_amdgcn_mfma_f32_16x16x32_bf16(af, bfv, acc1[mt], 0, 0, 0);
            }
        }
        // ---- write Ps[cell][chan] (bf16) ----
        #pragma unroll
        for (int mt = 0; mt < 5; ++mt) {
            #pragma unroll
            for (int g = 0; g < 4; ++g) {
                int cell = mt * 16 + quad * 4 + g;
                if (cell < AROWS_)
                    Ls[POFF_ + cell * PSTR_ + wave * 16 + m16] =
                        __float2bfloat16(acc1[mt][g]);
            }
        }
        __syncthreads();   // Ps ready; ALL waves past MFMA1 -> Bs(c) free

        // ---- MFMA2: acc2 += Ps(72x64) @ WcChunk(256x64)^T ----
        #pragma unroll
        for (int ks = 0; ks < 2; ++ks) {
            bf16x8 af[5];
            #pragma unroll
            for (int mt = 0; mt < 5; ++mt)
                af[mt] = *(const bf16x8*)&Ls[POFF_ + (mt * 16 + m16) * PSTR_ + ks * 32 + quad * 8];
            #pragma unroll
            for (int nt = 0; nt < 4; ++nt) {
                int n = wave * 64 + nt * 16 + m16;
                bf16x8 bfv = *(const bf16x8*)(Wc + (size_t)n * C_ + cbase0 + c * 64 + ks * 32 + quad * 8);
                #pragma unroll
                for (int mt = 0; mt < 5; ++mt)
                    acc2[mt][nt] = __builtin_amdgcn_mfma_f32_16x16x32_bf16(
                        af[mt], bfv, acc2[mt][nt], 0, 0, 0);
            }
        }

        // ---- write prefetched chunk c+1 into Bs (safe: Bs free since
        //      barrier2; next loop's barrier1 publishes it) ----
        if (c < NCHUNK_ - 1) {
            #pragma unroll
            for (int it = 0; it < 13; ++it) {
                int i = tid + it * 256;
                if (i < 64 * 49) {
                    int cr = i / 49, ch = i - cr * 49;
                    float4 v = vbuf[it];
                    bf4s t;
                    t.lo.x = __float2bfloat16(v.x); t.lo.y = __float2bfloat16(v.y);
                    t.hi.x = __float2bfloat16(v.z); t.hi.y = __float2bfloat16(v.w);
                    *(bf4s*)&Ls[BOFF_ + cr * SSTR_ + ch * 4] = t;
                }
            }
        }
    }

    // ---- epilogue: featp[cq][(b*72+row)*256 + col] ----
    float* dst = featp + (size_t)cq * ((size_t)128 * AROWS_ * 256);
    #pragma unroll
    for (int mt = 0; mt < 5; ++mt) {
        #pragma unroll
        for (int g = 0; g < 4; ++g) {
            int row = mt * 16 + quad * 4 + g;
            if (row < AROWS_) {
                #pragma unroll
                for (int nt = 0; nt < 4; ++nt)
                    dst[(size_t)(b * AROWS_ + row) * 256 + wave * 64 + nt * 16 + m16] =
                        acc2[mt][nt][g];
            }
        }
    }
}

// ---------------------------------------------------------------------------
// MFMA GEMM (fc1): h1 = relu(diff @ fc1_wp^T + b). 32x64 tile, BK=64.
// ---------------------------------------------------------------------------
__global__ __launch_bounds__(256, 4) void fc1_gemm_kernel(
    const __hip_bfloat16* __restrict__ A,    // diff (1024 x 2304)
    const __hip_bfloat16* __restrict__ Bm,   // fc1_wp (1024 x 2304)
    const float* __restrict__ bias,
    float* __restrict__ C)                   // h1 (1024 x 1024)
{
    const int tid = threadIdx.x;
    const int wave = tid >> 6, lane = tid & 63;
    const int r0 = blockIdx.y * 32, n0 = blockIdx.x * 64;
    const int wm = (wave >> 1) * 16, wn = (wave & 1) * 32;
    const int m16 = lane & 15, quad = lane >> 4;
    const int K = FEATD_;
    __shared__ __align__(16) __hip_bfloat16 As[32 * 64];
    __shared__ __align__(16) __hip_bfloat16 Bs[64 * 64];

    f32x4 acc[2];
    acc[0] = (f32x4){0.f, 0.f, 0.f, 0.f};
    acc[1] = (f32x4){0.f, 0.f, 0.f, 0.f};

    const int qa = wave * 64 + lane;                 // 0..255
    const int msA = qa >> 3, csA = (qa & 7) ^ (msA & 7);
    const int qb1 = qa + 256;
    const int msB1 = qb1 >> 3, csB1 = (qb1 & 7) ^ (msB1 & 7);
    const size_t rA  = (size_t)(r0 + msA)  * K + csA  * 8;
    const size_t rB0 = (size_t)(n0 + msA)  * K + csA  * 8;
    const size_t rB1 = (size_t)(n0 + msB1) * K + csB1 * 8;

    for (int k0 = 0; k0 < K; k0 += 64) {
        gld16(A  + rA  + k0, &As[wave * 512]);
        gld16(Bm + rB0 + k0, &Bs[wave * 512]);
        gld16(Bm + rB1 + k0, &Bs[2048 + wave * 512]);
        __syncthreads();
        #pragma unroll
        for (int ks = 0; ks < 2; ++ks) {
            bf16x8 af, bfv[2];
            int m = wm + m16;
            int cp = (ks * 4 + quad) ^ (m & 7);
            af = *(const bf16x8*)&As[(m * 8 + cp) * 8];
            #pragma unroll
            for (int t = 0; t < 2; ++t) {
                int n = wn + t * 16 + m16;
                int cq = (ks * 4 + quad) ^ (n & 7);
                bfv[t] = *(const bf16x8*)&Bs[(n * 8 + cq) * 8];
            }
            #pragma unroll
            for (int j = 0; j < 2; ++j)
                acc[j] = __builtin_amdgcn_mfma_f32_16x16x32_bf16(
                    af, bfv[j], acc[j], 0, 0, 0);
        }
        __syncthreads();
    }

    #pragma unroll
    for (int j = 0; j < 2; ++j) {
        int col = n0 + wn + j * 16 + m16;
        int rbase = r0 + wm + quad * 4;
        float bv = bias[col];
        #pragma unroll
        for (int g = 0; g < 4; ++g) {
            int r = rbase + g;
            float v = acc[j][g] + bv;
            C[(size_t)r * H1_ + col] = v > 0.f ? v : 0.f;
        }
    }
}

// ---------------------------------------------------------------------------
// fc1_w (1024 x 2304 fp32, k = o*9+hw) -> bf16 permuted (k' = hw*256+o)
// ---------------------------------------------------------------------------
__global__ __launch_bounds__(256) void fc1w_perm_kernel(
    const float* __restrict__ src, __hip_bfloat16* __restrict__ dst)
{
    int h = blockIdx.x;
    int tid = threadIdx.x;
    __shared__ float buf[FEATD_];
    const float* s = src + (size_t)h * FEATD_;
    #pragma unroll
    for (int it = 0; it < 9; ++it)
        buf[it * 256 + tid] = s[it * 256 + tid];
    __syncthreads();
    __hip_bfloat16* d = dst + (size_t)h * FEATD_;
    #pragma unroll
    for (int it = 0; it < 9; ++it) {
        int dd = it * 256 + tid;       // hw = it, o = tid
        d[dd] = __float2bfloat16(buf[tid * HWC_ + it]);
    }
}

// ---------------------------------------------------------------------------
// meandiff (FUSED invmap+meanb+diff): feat = sum of 4 featp parts.
//   inv computed per block from pids (scan -> LDS). mean in registers.
// ---------------------------------------------------------------------------
__global__ __launch_bounds__(256) void meandiff_kernel(
    const float* __restrict__ featp, const int* __restrict__ pids,
    __hip_bfloat16* __restrict__ diff)
{
    const size_t PART = (size_t)(B_ * N_) * FEATD_;
    int p = blockIdx.x;
    int d = blockIdx.y * 256 + threadIdx.x;
    __shared__ int invs[B_];
    if (threadIdx.x < B_) {
        int bb = threadIdx.x;
        int v = -1;
        #pragma unroll
        for (int n = 0; n < N_; ++n)
            if (pids[bb * N_ + n] == p) v = n;
        invs[bb] = v;
    }
    __syncthreads();

    float acc = 0.0f;
    #pragma unroll 4
    for (int b = 0; b < B_; ++b) {
        int n = invs[b];
        if (n >= 0) {
            size_t idx = (size_t)(b * N_ + n) * FEATD_ + d;
            acc += (featp[idx] + featp[idx + PART]) +
                   (featp[idx + 2 * PART] + featp[idx + 3 * PART]);
        }
    }
    float mean = acc * (1.0f / (float)B_);
    #pragma unroll 4
    for (int b = 0; b < B_; ++b) {
        int n = invs[b];
        if (n >= 0) {
            size_t idx = (size_t)(b * N_ + n) * FEATD_ + d;
            float v = (featp[idx] + featp[idx + PART]) +
                      (featp[idx + 2 * PART] + featp[idx + 3 * PART]);
            diff[idx] = __float2bfloat16(mean - v);
        }
    }
}

// ---------------------------------------------------------------------------
// fc2: out[bn][o] = h1[bn] . fc2_w[o] + fc2_b[o]
// ---------------------------------------------------------------------------
__global__ __launch_bounds__(256) void fc2_kernel(
    const float* __restrict__ h1, const float* __restrict__ fc2_w,
    const float* __restrict__ fc2_b, float* __restrict__ out)
{
    int bn = blockIdx.x;
    int tid = threadIdx.x;
    __shared__ __align__(16) float row[H1_];
    __shared__ float partial[32][8];
    ((float4*)row)[tid] = ((const float4*)(h1 + (size_t)bn * H1_))[tid];
    __syncthreads();
    int o = tid >> 3, part = tid & 7;
    float acc = 0.0f;
    if (o < O_) {
        const float* wrow = fc2_w + (size_t)o * H1_ + part * 128;
        const float* hrow = row + part * 128;
        #pragma unroll 4
        for (int j = 0; j < 128; ++j) acc += hrow[j] * wrow[j];
    }
    partial[o][part] = acc;
    __syncthreads();
    if (part == 0 && o < O_) {
        float s = fc2_b[o];
        #pragma unroll
        for (int p = 0; p < 8; ++p) s += partial[o][p];
        out[(size_t)bn * O_ + o] = s;
    }
}

// ---------------------------------------------------------------------------
// Launch
// ---------------------------------------------------------------------------
extern "C" void kernel_launch(void* const* d_in, const int* in_sizes, int n_in,
                              void* d_out, int out_size, void* d_ws, size_t ws_size,
                              hipStream_t stream) {
    const float* fmap  = (const float*)d_in[0];
    const float* boxes = (const float*)d_in[1];
    const int*   pids  = (const int*)  d_in[2];
    const float* w1    = (const float*)d_in[3];
    const float* w2    = (const float*)d_in[4];
    const float* fc1_w = (const float*)d_in[5];
    const float* fc1_b = (const float*)d_in[6];
    const float* fc2_w = (const float*)d_in[7];
    const float* fc2_b = (const float*)d_in[8];
    float* out = (float*)d_out;

    // workspace layout (all 16B aligned)
    char* wsb = (char*)d_ws;
    __hip_bfloat16* Wc    = (__hip_bfloat16*)wsb;                       // 256*1024
    __hip_bfloat16* fc1wp = Wc + 256 * 1024;                            // 1024*2304
    __hip_bfloat16* diffp = fc1wp + (size_t)H1_ * FEATD_;               // 1024*2304
    float* featp  = (float*)(diffp + (size_t)H1_ * FEATD_);             // 4*1024*2304
    float* h1     = featp + 4 * (size_t)(B_ * N_) * FEATD_;             // 1024*1024
    float* wpart  = h1 + (size_t)(B_ * N_) * H1_;                       // 8*256*1024

    hipLaunchKernelGGL(wcombine_split_kernel, dim3(16, 4, 8), dim3(256), 0, stream,
                       w1, w2, wpart);
    hipLaunchKernelGGL(wc_reduce_kernel, dim3(1024), dim3(256), 0, stream,
                       wpart, Wc);
    hipLaunchKernelGGL(poolmix_kernel, dim3(4, 128), dim3(256), 0, stream,
                       fmap, boxes, Wc, featp);
    hipLaunchKernelGGL(fc1w_perm_kernel, dim3(1024), dim3(256), 0, stream,
                       fc1_w, fc1wp);
    hipLaunchKernelGGL(meandiff_kernel, dim3(20, 9), dim3(256), 0, stream,
                       featp, pids, diffp);
    hipLaunchKernelGGL(fc1_gemm_kernel, dim3(16, 32), dim3(256), 0, stream,
                       diffp, fc1wp, fc1_b, h1);
    hipLaunchKernelGGL(fc2_kernel, dim3(1024), dim3(256), 0, stream,
                       h1, fc2_w, fc2_b, out);
}

// Round 13
// 293.359 us; speedup vs baseline: 1.0341x; 1.0092x over previous
//
#include <hip/hip_runtime.h>
#include <hip/hip_bf16.h>
#include <cstddef>
#include <cstdint>

// ---------------------------------------------------------------------------
// Problem constants
// ---------------------------------------------------------------------------
#define B_   128
#define N_   8
#define C_   1024
#define FS_  14
#define POS_ 196            // 14*14
#define P_   20
#define HWC_ 9              // 3*3 cells
#define CMID_ 256
#define FEATD_ 2304         // CMID*HWC
#define H1_  1024
#define O_   27

typedef __attribute__((ext_vector_type(8))) short bf16x8;   // 8 bf16 (4 VGPRs)
typedef __attribute__((ext_vector_type(4))) float f32x4;

// async global->LDS, 16B per lane; LDS dest = wave-uniform base + lane*16
__device__ __forceinline__ void gld16(const void* g, void* l) {
    __builtin_amdgcn_global_load_lds(
        (const __attribute__((address_space(1))) unsigned int*)g,
        (__attribute__((address_space(3))) unsigned int*)l, 16, 0, 0);
}

__device__ __forceinline__ short bfs(float f) {
    __hip_bfloat16 h = __float2bfloat16(f);
    return *(short*)&h;
}

// ---------------------------------------------------------------------------
// Kernel 1a: split-K partials of Wc = w2 @ w1
// ---------------------------------------------------------------------------
__global__ __launch_bounds__(256) void wcombine_split_kernel(
    const float* __restrict__ w1,   // (512,1024)
    const float* __restrict__ w2,   // (256,512)
    float* __restrict__ wpart)      // (8,256,1024) fp32
{
    const int tid = threadIdx.x;
    const int tx = tid & 15, ty = tid >> 4;
    const int c0 = blockIdx.x * 64;
    const int o0 = blockIdx.y * 64;
    const int kb = blockIdx.z * 64;
    __shared__ __align__(16) float As[16][68];
    __shared__ __align__(16) float Bs[16][68];
    float acc[4][4] = {};
    for (int k0 = kb; k0 < kb + 64; k0 += 16) {
        for (int i = tid; i < 64 * 16; i += 256) {
            int k = i & 15, m = i >> 4;
            As[k][m] = w2[(size_t)(o0 + m) * 512 + k0 + k];
        }
        for (int i = tid; i < 64 * 16; i += 256) {
            int n = i & 63, k = i >> 6;
            Bs[k][n] = w1[(size_t)(k0 + k) * 1024 + c0 + n];
        }
        __syncthreads();
        #pragma unroll
        for (int k = 0; k < 16; ++k) {
            float4 a = *(const float4*)&As[k][ty * 4];
            float4 b = *(const float4*)&Bs[k][tx * 4];
            float av[4] = {a.x, a.y, a.z, a.w};
            float bv[4] = {b.x, b.y, b.z, b.w};
            #pragma unroll
            for (int i = 0; i < 4; ++i)
                #pragma unroll
                for (int j = 0; j < 4; ++j)
                    acc[i][j] += av[i] * bv[j];
        }
        __syncthreads();
    }
    float* dst = wpart + (size_t)blockIdx.z * (256 * 1024);
    for (int i = 0; i < 4; ++i) {
        float4 v = make_float4(acc[i][0], acc[i][1], acc[i][2], acc[i][3]);
        *(float4*)&dst[(size_t)(o0 + ty * 4 + i) * 1024 + c0 + tx * 4] = v;
    }
}

// ---------------------------------------------------------------------------
// Kernel 1b: Wc = bf16( sum_z wpart[z] )
// ---------------------------------------------------------------------------
__global__ __launch_bounds__(256) void wc_reduce_kernel(
    const float* __restrict__ wpart, __hip_bfloat16* __restrict__ Wc)
{
    int idx = blockIdx.x * 256 + threadIdx.x;
    float s = 0.f;
    #pragma unroll
    for (int z = 0; z < 8; ++z) s += wpart[(size_t)z * (256 * 1024) + idx];
    Wc[idx] = __float2bfloat16(s);
}

// ---------------------------------------------------------------------------
// Kernel 2 (FUSED, v3): poolmix with DIRECT-FROM-GLOBAL fmap fragments.
//   R12 post-mortem: 8 rounds of variants that stage fmap through LDS all
//   land 55-68 µs (occupancy 1->6 blk/CU, VALU 2.5x down, two algorithms).
//   The invariant is the staging structure: load->convert->ds_write->
//   barrier->consume. This version deletes it: MFMA1's B-fragment (8
//   consecutive pos of one channel row) is loaded straight into VGPRs
//   (2 float4/kk; 128B contiguous per quad-group = coalesced), converted
//   in registers. No Bs, no stage barrier; the 2 barriers/chunk remain
//   only for the Ps hand-off. A's LDS k-pad is zero, so B's k>=196 lanes
//   multiply into 0; only kk=6 needs explicit zeros + a quad0-only load
//   (pos 192..195) to avoid OOB reads at the buffer tail.
//   Chunk c+1's loads issue right after convert(c) -> MFMA1+Ps+MFMA2
//   cover their latency. LDS 43 KB. Same values at same rounding points
//   as R12 -> absmax unchanged.
// ---------------------------------------------------------------------------
#define SSTR_  232            // A row stride in bf16 (zeros at 196..231)
#define AROWS_ 72
#define PSTR_  72                      // Ps row stride
#define POFF_  (AROWS_ * SSTR_)        // Ps base (elems)
#define NCHUNK_ 4                      // 4 x 64 channels per block
__global__ __launch_bounds__(256, 2) void poolmix_kernel(
    const float* __restrict__ fmap,          // (128,1024,196)
    const float* __restrict__ boxes,         // (128,8,4)
    const __hip_bfloat16* __restrict__ Wc,   // (256,1024)
    float* __restrict__ featp)               // (4, 128*72, 256) fp32
{
    const int cq = blockIdx.x;               // channel quarter 0..3
    const int b  = blockIdx.y;
    const int tid = threadIdx.x;
    const int wave = tid >> 6, lane = tid & 63;
    const int m16 = lane & 15, quad = lane >> 4;
    __shared__ __align__(16) __hip_bfloat16 Ls[POFF_ + AROWS_ * PSTR_];

    const int cbase0 = cq * 256;
    // per-lane fmap row for MFMA1 B-fragments: channel nrow of chunk c
    const int nrow = wave * 16 + m16;
    const float* frow0 = fmap + ((size_t)b * C_ + cbase0 + nrow) * POS_;

    // ---- issue chunk-0 fragment loads FIRST (latency hidden by A build) ----
    float4 pf[13];
    {
        const float* fr = frow0 + quad * 8;
        #pragma unroll
        for (int kk = 0; kk < 6; ++kk) {
            pf[2 * kk]     = *(const float4*)(fr + kk * 32);
            pf[2 * kk + 1] = *(const float4*)(fr + kk * 32 + 4);
        }
        if (quad == 0) pf[12] = *(const float4*)(frow0 + 192);
    }

    // ---- build Wpool A rows (separable outer product; R9-validated) ----
    if (tid < AROWS_) {
        const int m = tid;
        const int n = m / 9, cell = m - n * 9;
        const int chh = cell / 3, cww = cell % 3;
        float4 bx = *(const float4*)(boxes + ((size_t)b * N_ + n) * 4);
        float bw = (bx.z - bx.x) * (1.0f / 3.0f);
        float bh = (bx.w - bx.y) * (1.0f / 3.0f);
        float ypro[FS_], xpro[FS_];
        #pragma unroll
        for (int k = 0; k < FS_; ++k) { ypro[k] = 0.f; xpro[k] = 0.f; }
        #pragma unroll
        for (int s = 0; s < 2; ++s) {
            float yy = bx.y + ((float)(2 * chh + s) + 0.5f) * 0.5f * bh;
            bool vy = (yy > -1.0f) && (yy < (float)FS_);
            float y = fminf(fmaxf(yy, 0.0f), (float)(FS_ - 1));
            int y0 = (int)floorf(y);
            int y1i = min(y0 + 1, FS_ - 1);
            float ly = y - (float)y0, hy = 1.0f - ly;
            float qy = vy ? 0.5f : 0.0f;
            float w0 = hy * qy, w1 = ly * qy;
            #pragma unroll
            for (int k = 0; k < FS_; ++k)
                ypro[k] += (k == y0 ? w0 : 0.f) + (k == y1i ? w1 : 0.f);
            float xx = bx.x + ((float)(2 * cww + s) + 0.5f) * 0.5f * bw;
            bool vx = (xx > -1.0f) && (xx < (float)FS_);
            float x = fminf(fmaxf(xx, 0.0f), (float)(FS_ - 1));
            int x0 = (int)floorf(x);
            int x1i = min(x0 + 1, FS_ - 1);
            float lx = x - (float)x0, hx = 1.0f - lx;
            float qx = vx ? 0.5f : 0.0f;
            float u0 = hx * qx, u1 = lx * qx;
            #pragma unroll
            for (int k = 0; k < FS_; ++k)
                xpro[k] += (k == x0 ? u0 : 0.f) + (k == x1i ? u1 : 0.f);
        }
        __hip_bfloat162* row2 = (__hip_bfloat162*)&Ls[m * SSTR_];
        #pragma unroll
        for (int p = 0; p < 98; ++p) {
            const int i0 = 2 * p, i1 = 2 * p + 1;
            __hip_bfloat162 t;
            t.x = __float2bfloat16(ypro[i0 / FS_] * xpro[i0 % FS_]);
            t.y = __float2bfloat16(ypro[i1 / FS_] * xpro[i1 % FS_]);
            row2[p] = t;
        }
        const __hip_bfloat16 z16 = __float2bfloat16(0.0f);
        #pragma unroll
        for (int p = 98; p < SSTR_ / 2; ++p) {
            __hip_bfloat162 t; t.x = z16; t.y = z16;
            row2[p] = t;
        }
    }
    __syncthreads();   // A ready

    // persistent output accumulator: wave owns cols [wave*64, wave*64+64)
    f32x4 acc2[5][4];
    #pragma unroll
    for (int mt = 0; mt < 5; ++mt)
        #pragma unroll
        for (int nt = 0; nt < 4; ++nt)
            acc2[mt][nt] = (f32x4){0.f, 0.f, 0.f, 0.f};

    for (int c = 0; c < NCHUNK_; ++c) {
        // ---- convert chunk c fragments to bf16 in registers ----
        bf16x8 bf[7];
        #pragma unroll
        for (int kk = 0; kk < 6; ++kk) {
            float4 a = pf[2 * kk], bb = pf[2 * kk + 1];
            bf16x8 r;
            r[0] = bfs(a.x); r[1] = bfs(a.y); r[2] = bfs(a.z); r[3] = bfs(a.w);
            r[4] = bfs(bb.x); r[5] = bfs(bb.y); r[6] = bfs(bb.z); r[7] = bfs(bb.w);
            bf[kk] = r;
        }
        {
            bf16x8 r = (bf16x8){0, 0, 0, 0, 0, 0, 0, 0};
            if (quad == 0) {
                float4 a = pf[12];
                r[0] = bfs(a.x); r[1] = bfs(a.y); r[2] = bfs(a.z); r[3] = bfs(a.w);
            }
            bf[6] = r;   // k>=196 slots zero; A pad is zero anyway
        }

        // ---- issue chunk c+1 fragment loads (pf regs now free) ----
        if (c < NCHUNK_ - 1) {
            const float* frow = frow0 + (size_t)((c + 1) * 64) * POS_;
            const float* fr = frow + quad * 8;
            #pragma unroll
            for (int kk = 0; kk < 6; ++kk) {
                pf[2 * kk]     = *(const float4*)(fr + kk * 32);
                pf[2 * kk + 1] = *(const float4*)(fr + kk * 32 + 4);
            }
            if (quad == 0) pf[12] = *(const float4*)(frow + 192);
        }

        // ---- MFMA1: pooled_chunk(72x64) = A @ fmapChunk^T ----
        f32x4 acc1[5];
        #pragma unroll
        for (int mt = 0; mt < 5; ++mt) acc1[mt] = (f32x4){0.f, 0.f, 0.f, 0.f};
        #pragma unroll
        for (int kk = 0; kk < 7; ++kk) {
            #pragma unroll
            for (int mt = 0; mt < 5; ++mt) {
                bf16x8 af = *(const bf16x8*)&Ls[(mt * 16 + m16) * SSTR_ + kk * 32 + quad * 8];
                acc1[mt] = __builtin_amdgcn_mfma_f32_16x16x32_bf16(af, bf[kk], acc1[mt], 0, 0, 0);
            }
        }
        __syncthreads();   // all waves past MFMA2(c-1): Ps writable

        // ---- write Ps[cell][chan] (bf16) ----
        #pragma unroll
        for (int mt = 0; mt < 5; ++mt) {
            #pragma unroll
            for (int g = 0; g < 4; ++g) {
                int cell = mt * 16 + quad * 4 + g;
                if (cell < AROWS_)
                    Ls[POFF_ + cell * PSTR_ + wave * 16 + m16] =
                        __float2bfloat16(acc1[mt][g]);
            }
        }
        __syncthreads();   // Ps ready

        // ---- MFMA2: acc2 += Ps(72x64) @ WcChunk(256x64)^T ----
        #pragma unroll
        for (int ks = 0; ks < 2; ++ks) {
            bf16x8 af[5];
            #pragma unroll
            for (int mt = 0; mt < 5; ++mt)
                af[mt] = *(const bf16x8*)&Ls[POFF_ + (mt * 16 + m16) * PSTR_ + ks * 32 + quad * 8];
            #pragma unroll
            for (int nt = 0; nt < 4; ++nt) {
                int n = wave * 64 + nt * 16 + m16;
                bf16x8 bfv = *(const bf16x8*)(Wc + (size_t)n * C_ + cbase0 + c * 64 + ks * 32 + quad * 8);
                #pragma unroll
                for (int mt = 0; mt < 5; ++mt)
                    acc2[mt][nt] = __builtin_amdgcn_mfma_f32_16x16x32_bf16(
                        af[mt], bfv, acc2[mt][nt], 0, 0, 0);
            }
        }
    }

    // ---- epilogue: featp[cq][(b*72+row)*256 + col] ----
    float* dst = featp + (size_t)cq * ((size_t)128 * AROWS_ * 256);
    #pragma unroll
    for (int mt = 0; mt < 5; ++mt) {
        #pragma unroll
        for (int g = 0; g < 4; ++g) {
            int row = mt * 16 + quad * 4 + g;
            if (row < AROWS_) {
                #pragma unroll
                for (int nt = 0; nt < 4; ++nt)
                    dst[(size_t)(b * AROWS_ + row) * 256 + wave * 64 + nt * 16 + m16] =
                        acc2[mt][nt][g];
            }
        }
    }
}

// ---------------------------------------------------------------------------
// MFMA GEMM (fc1): h1 = relu(diff @ fc1_wp^T + b). 32x64 tile, BK=64.
// ---------------------------------------------------------------------------
__global__ __launch_bounds__(256, 4) void fc1_gemm_kernel(
    const __hip_bfloat16* __restrict__ A,    // diff (1024 x 2304)
    const __hip_bfloat16* __restrict__ Bm,   // fc1_wp (1024 x 2304)
    const float* __restrict__ bias,
    float* __restrict__ C)                   // h1 (1024 x 1024)
{
    const int tid = threadIdx.x;
    const int wave = tid >> 6, lane = tid & 63;
    const int r0 = blockIdx.y * 32, n0 = blockIdx.x * 64;
    const int wm = (wave >> 1) * 16, wn = (wave & 1) * 32;
    const int m16 = lane & 15, quad = lane >> 4;
    const int K = FEATD_;
    __shared__ __align__(16) __hip_bfloat16 As[32 * 64];
    __shared__ __align__(16) __hip_bfloat16 Bs[64 * 64];

    f32x4 acc[2];
    acc[0] = (f32x4){0.f, 0.f, 0.f, 0.f};
    acc[1] = (f32x4){0.f, 0.f, 0.f, 0.f};

    const int qa = wave * 64 + lane;                 // 0..255
    const int msA = qa >> 3, csA = (qa & 7) ^ (msA & 7);
    const int qb1 = qa + 256;
    const int msB1 = qb1 >> 3, csB1 = (qb1 & 7) ^ (msB1 & 7);
    const size_t rA  = (size_t)(r0 + msA)  * K + csA  * 8;
    const size_t rB0 = (size_t)(n0 + msA)  * K + csA  * 8;
    const size_t rB1 = (size_t)(n0 + msB1) * K + csB1 * 8;

    for (int k0 = 0; k0 < K; k0 += 64) {
        gld16(A  + rA  + k0, &As[wave * 512]);
        gld16(Bm + rB0 + k0, &Bs[wave * 512]);
        gld16(Bm + rB1 + k0, &Bs[2048 + wave * 512]);
        __syncthreads();
        #pragma unroll
        for (int ks = 0; ks < 2; ++ks) {
            bf16x8 af, bfv[2];
            int m = wm + m16;
            int cp = (ks * 4 + quad) ^ (m & 7);
            af = *(const bf16x8*)&As[(m * 8 + cp) * 8];
            #pragma unroll
            for (int t = 0; t < 2; ++t) {
                int n = wn + t * 16 + m16;
                int cq = (ks * 4 + quad) ^ (n & 7);
                bfv[t] = *(const bf16x8*)&Bs[(n * 8 + cq) * 8];
            }
            #pragma unroll
            for (int j = 0; j < 2; ++j)
                acc[j] = __builtin_amdgcn_mfma_f32_16x16x32_bf16(
                    af, bfv[j], acc[j], 0, 0, 0);
        }
        __syncthreads();
    }

    #pragma unroll
    for (int j = 0; j < 2; ++j) {
        int col = n0 + wn + j * 16 + m16;
        int rbase = r0 + wm + quad * 4;
        float bv = bias[col];
        #pragma unroll
        for (int g = 0; g < 4; ++g) {
            int r = rbase + g;
            float v = acc[j][g] + bv;
            C[(size_t)r * H1_ + col] = v > 0.f ? v : 0.f;
        }
    }
}

// ---------------------------------------------------------------------------
// fc1_w (1024 x 2304 fp32, k = o*9+hw) -> bf16 permuted (k' = hw*256+o)
// ---------------------------------------------------------------------------
__global__ __launch_bounds__(256) void fc1w_perm_kernel(
    const float* __restrict__ src, __hip_bfloat16* __restrict__ dst)
{
    int h = blockIdx.x;
    int tid = threadIdx.x;
    __shared__ float buf[FEATD_];
    const float* s = src + (size_t)h * FEATD_;
    #pragma unroll
    for (int it = 0; it < 9; ++it)
        buf[it * 256 + tid] = s[it * 256 + tid];
    __syncthreads();
    __hip_bfloat16* d = dst + (size_t)h * FEATD_;
    #pragma unroll
    for (int it = 0; it < 9; ++it) {
        int dd = it * 256 + tid;       // hw = it, o = tid
        d[dd] = __float2bfloat16(buf[tid * HWC_ + it]);
    }
}

// ---------------------------------------------------------------------------
// meandiff (FUSED invmap+meanb+diff): feat = sum of 4 featp parts.
// ---------------------------------------------------------------------------
__global__ __launch_bounds__(256) void meandiff_kernel(
    const float* __restrict__ featp, const int* __restrict__ pids,
    __hip_bfloat16* __restrict__ diff)
{
    const size_t PART = (size_t)(B_ * N_) * FEATD_;
    int p = blockIdx.x;
    int d = blockIdx.y * 256 + threadIdx.x;
    __shared__ int invs[B_];
    if (threadIdx.x < B_) {
        int bb = threadIdx.x;
        int v = -1;
        #pragma unroll
        for (int n = 0; n < N_; ++n)
            if (pids[bb * N_ + n] == p) v = n;
        invs[bb] = v;
    }
    __syncthreads();

    float acc = 0.0f;
    #pragma unroll 4
    for (int b = 0; b < B_; ++b) {
        int n = invs[b];
        if (n >= 0) {
            size_t idx = (size_t)(b * N_ + n) * FEATD_ + d;
            acc += (featp[idx] + featp[idx + PART]) +
                   (featp[idx + 2 * PART] + featp[idx + 3 * PART]);
        }
    }
    float mean = acc * (1.0f / (float)B_);
    #pragma unroll 4
    for (int b = 0; b < B_; ++b) {
        int n = invs[b];
        if (n >= 0) {
            size_t idx = (size_t)(b * N_ + n) * FEATD_ + d;
            float v = (featp[idx] + featp[idx + PART]) +
                      (featp[idx + 2 * PART] + featp[idx + 3 * PART]);
            diff[idx] = __float2bfloat16(mean - v);
        }
    }
}

// ---------------------------------------------------------------------------
// fc2: out[bn][o] = h1[bn] . fc2_w[o] + fc2_b[o]
// ---------------------------------------------------------------------------
__global__ __launch_bounds__(256) void fc2_kernel(
    const float* __restrict__ h1, const float* __restrict__ fc2_w,
    const float* __restrict__ fc2_b, float* __restrict__ out)
{
    int bn = blockIdx.x;
    int tid = threadIdx.x;
    __shared__ __align__(16) float row[H1_];
    __shared__ float partial[32][8];
    ((float4*)row)[tid] = ((const float4*)(h1 + (size_t)bn * H1_))[tid];
    __syncthreads();
    int o = tid >> 3, part = tid & 7;
    float acc = 0.0f;
    if (o < O_) {
        const float* wrow = fc2_w + (size_t)o * H1_ + part * 128;
        const float* hrow = row + part * 128;
        #pragma unroll 4
        for (int j = 0; j < 128; ++j) acc += hrow[j] * wrow[j];
    }
    partial[o][part] = acc;
    __syncthreads();
    if (part == 0 && o < O_) {
        float s = fc2_b[o];
        #pragma unroll
        for (int p = 0; p < 8; ++p) s += partial[o][p];
        out[(size_t)bn * O_ + o] = s;
    }
}

// ---------------------------------------------------------------------------
// Launch
// ---------------------------------------------------------------------------
extern "C" void kernel_launch(void* const* d_in, const int* in_sizes, int n_in,
                              void* d_out, int out_size, void* d_ws, size_t ws_size,
                              hipStream_t stream) {
    const float* fmap  = (const float*)d_in[0];
    const float* boxes = (const float*)d_in[1];
    const int*   pids  = (const int*)  d_in[2];
    const float* w1    = (const float*)d_in[3];
    const float* w2    = (const float*)d_in[4];
    const float* fc1_w = (const float*)d_in[5];
    const float* fc1_b = (const float*)d_in[6];
    const float* fc2_w = (const float*)d_in[7];
    const float* fc2_b = (const float*)d_in[8];
    float* out = (float*)d_out;

    // workspace layout (all 16B aligned)
    char* wsb = (char*)d_ws;
    __hip_bfloat16* Wc    = (__hip_bfloat16*)wsb;                       // 256*1024
    __hip_bfloat16* fc1wp = Wc + 256 * 1024;                            // 1024*2304
    __hip_bfloat16* diffp = fc1wp + (size_t)H1_ * FEATD_;               // 1024*2304
    float* featp  = (float*)(diffp + (size_t)H1_ * FEATD_);             // 4*1024*2304
    float* h1     = featp + 4 * (size_t)(B_ * N_) * FEATD_;             // 1024*1024
    float* wpart  = h1 + (size_t)(B_ * N_) * H1_;                       // 8*256*1024

    hipLaunchKernelGGL(wcombine_split_kernel, dim3(16, 4, 8), dim3(256), 0, stream,
                       w1, w2, wpart);
    hipLaunchKernelGGL(wc_reduce_kernel, dim3(1024), dim3(256), 0, stream,
                       wpart, Wc);
    hipLaunchKernelGGL(poolmix_kernel, dim3(4, 128), dim3(256), 0, stream,
                       fmap, boxes, Wc, featp);
    hipLaunchKernelGGL(fc1w_perm_kernel, dim3(1024), dim3(256), 0, stream,
                       fc1_w, fc1wp);
    hipLaunchKernelGGL(meandiff_kernel, dim3(20, 9), dim3(256), 0, stream,
                       featp, pids, diffp);
    hipLaunchKernelGGL(fc1_gemm_kernel, dim3(16, 32), dim3(256), 0, stream,
                       diffp, fc1wp, fc1_b, h1);
    hipLaunchKernelGGL(fc2_kernel, dim3(1024), dim3(256), 0, stream,
                       h1, fc2_w, fc2_b, out);
}